// Round 1
// 1166.611 us; speedup vs baseline: 1.0537x; 1.0537x over previous
//
#include <hip/hip_runtime.h>
#include <hip/hip_fp16.h>
#include <stdint.h>

namespace {
constexpr int B = 4, C = 384, Wd = 256, HW = 65536;
constexpr int NH = 8, HD = 48, SH = 4;
constexpr float SCALE = 0.14433756729740643f;   // 48^-0.5

// ---------------- kernel 1: Qg[b,c] = mean over HW of X_f ----------------
__global__ __launch_bounds__(256) void k_mean(const float* __restrict__ Xf,
                                              float* __restrict__ Qg) {
  int bc = blockIdx.x;
  const float4* p = reinterpret_cast<const float4*>(Xf + (size_t)bc * HW);
  float s = 0.f;
  for (int it = threadIdx.x; it < HW / 4; it += 256) {
    float4 v = p[it];
    s += (v.x + v.y) + (v.z + v.w);
  }
  __shared__ float red[256];
  red[threadIdx.x] = s;
  __syncthreads();
  for (int off = 128; off > 0; off >>= 1) {
    if (threadIdx.x < off) red[threadIdx.x] += red[threadIdx.x + off];
    __syncthreads();
  }
  if (threadIdx.x == 0) Qg[bc] = red[0] * (1.0f / HW);
}

// ---------------- kernel 2: Q = Qg@Wq.T + bq ; Qk[b,c,h] = sum_d Q[b,h,d]*Wk[h*HD+d,c]
// (transposed [b][c][h] output so the fused kernel can bulk-copy it to LDS)
// also zeroes Y for the fused kernel's atomic accumulation.
__global__ __launch_bounds__(256) void k_proj(const float* __restrict__ Qg,
                                              const float* __restrict__ Wq,
                                              const float* __restrict__ bq,
                                              const float* __restrict__ Wk,
                                              float* __restrict__ Qk,
                                              float* __restrict__ Y) {
  int t = threadIdx.x;
  for (int i = t; i < B * NH * C; i += 256) Y[i] = 0.f;
  __shared__ float Qs[B * C];
  for (int idx = t; idx < B * C; idx += 256) {
    int b = idx / C, o = idx % C;
    const float* qg = Qg + b * C;
    const float* w = Wq + (size_t)o * C;
    float s = bq[o];
    for (int c = 0; c < C; c++) s += qg[c] * w[c];
    Qs[idx] = s;
  }
  __syncthreads();
  for (int idx = t; idx < B * NH * C; idx += 256) {
    int c = idx % C;
    int bh = idx / C;
    int h = bh % NH, b = bh / NH;
    float s = 0.f;
    for (int d = 0; d < HD; d++)
      s += Qs[b * C + h * HD + d] * Wk[(size_t)(h * HD + d) * C + c];
    Qk[((size_t)b * C + c) * NH + h] = s;   // [b][c][h]
  }
  // bk-term is constant per (b,h) across the 64 window slots -> softmax-invariant, dropped
}

// ---------------- kernel 3: fused scores + softmax + pool, one block per (b, window)
// Window patch (8x8 px, all 384 ch) streamed from HBM ONCE: scores accumulate in
// registers during the load, patch parked in LDS as fp16, 64-slot softmax in-wave,
// pool from LDS, atomicAdd per-window partial into Y[b][h][c].
__global__ __launch_bounds__(256) void k_attn(const float* __restrict__ Xs,
                                              const float* __restrict__ Qk,
                                              float* __restrict__ Y) {
  __shared__ __align__(16) __half Xh[C][66];       // 50688 B, +2 pad halves/row
  __shared__ __align__(16) float Qks[C][8];        // 12288 B
  __shared__ __align__(16) float Sred[4][16][33];  // 8448 B, per-wave score partials
  __shared__ __align__(16) float Wl[64][12];       // 3072 B, softmax weights [p][h]

  // XCD-contiguous swizzle: adjacent windows (sharing 128B lines) -> same XCD L2
  int raw = blockIdx.x;
  int bw = (raw & 7) * 512 + (raw >> 3);           // 4096 = 8 * 512, bijective
  int b = bw >> 10, w = bw & 1023;
  int wi = w >> 5, wj = w & 31;
  int t = threadIdx.x;

  // phase 0: Qk[b] -> LDS (3072 floats)
  {
    const float4* src = reinterpret_cast<const float4*>(Qk + (size_t)b * C * NH);
    float4* dst = reinterpret_cast<float4*>(&Qks[0][0]);
    for (int i = t; i < C * NH / 4; i += 256) dst[i] = src[i];
  }
  __syncthreads();

  // phase A: thread = (q = px quad: row r, col-quad jq; g = channel subgroup)
  int q = t & 15, g = t >> 4;
  int r = q >> 1, jq = q & 1;
  int si = ((wi << 3) + r + 256 - SH) & 255;                 // rolled -> source row
  int sj = ((wj << 3) + (jq << 2) + 256 - SH) & 255;         // 4-aligned, no straddle
  const float* xb = Xs + (((size_t)b * C + g) << 16) + si * Wd + sj;

  float sp[4][8];
#pragma unroll
  for (int e = 0; e < 4; e++)
#pragma unroll
    for (int h = 0; h < 8; h++) sp[e][h] = 0.f;

#pragma unroll 4
  for (int k = 0; k < 24; k++) {
    int c = g + (k << 4);
    float4 xv = *reinterpret_cast<const float4*>(xb + ((size_t)(k << 4) << 16));
    const float4* qp = reinterpret_cast<const float4*>(&Qks[c][0]);
    float4 qa = qp[0], qb = qp[1];
    __half2 h01 = __float22half2_rn(make_float2(xv.x, xv.y));
    __half2 h23 = __float22half2_rn(make_float2(xv.z, xv.w));
    __half2* xw = reinterpret_cast<__half2*>(&Xh[c][q << 2]);
    xw[0] = h01;
    xw[1] = h23;
    float xa[4] = {xv.x, xv.y, xv.z, xv.w};
#pragma unroll
    for (int e = 0; e < 4; e++) {
      sp[e][0] += xa[e] * qa.x; sp[e][1] += xa[e] * qa.y;
      sp[e][2] += xa[e] * qa.z; sp[e][3] += xa[e] * qa.w;
      sp[e][4] += xa[e] * qb.x; sp[e][5] += xa[e] * qb.y;
      sp[e][6] += xa[e] * qb.z; sp[e][7] += xa[e] * qb.w;
    }
  }

  // intra-wave reduce over the 4 channel subgroups resident in this wave
#pragma unroll
  for (int e = 0; e < 4; e++)
#pragma unroll
    for (int h = 0; h < 8; h++) {
      float v = sp[e][h];
      v += __shfl_xor(v, 16);
      v += __shfl_xor(v, 32);
      sp[e][h] = v;
    }
  int wv = t >> 6;
  int gg = g & 3;   // lane's subgroup slot within the wave -> writes px e=gg of its quad
#pragma unroll
  for (int h = 0; h < 8; h++) {
    // static-index select (runtime-indexed reg array would spill to scratch)
    float v = (gg == 0) ? sp[0][h] : (gg == 1) ? sp[1][h] : (gg == 2) ? sp[2][h] : sp[3][h];
    Sred[wv][q][gg * 8 + h] = v;
  }
  __syncthreads();

  // softmax: thread = (p = window slot 0..63, hg -> heads 2hg,2hg+1); wave = window
  int p = t & 63, hg = t >> 6;
  int qq = p >> 2, ee = p & 3;
#pragma unroll
  for (int hh = 0; hh < 2; hh++) {
    int h = hg * 2 + hh;
    float s = Sred[0][qq][ee * 8 + h] + Sred[1][qq][ee * 8 + h] +
              Sred[2][qq][ee * 8 + h] + Sred[3][qq][ee * 8 + h];
    s *= SCALE;
    float m = s;
#pragma unroll
    for (int off = 32; off > 0; off >>= 1) m = fmaxf(m, __shfl_xor(m, off));
    float e = __expf(s - m);
    float sum = e;
#pragma unroll
    for (int off = 32; off > 0; off >>= 1) sum += __shfl_xor(sum, off);
    Wl[p][h] = e / sum;
  }
  __syncthreads();

  // phase C: pool. thread = channel c; Wl rows are lane-uniform -> LDS broadcast
  for (int c = t; c < C; c += 256) {
    float acc[8];
#pragma unroll
    for (int h = 0; h < 8; h++) acc[h] = 0.f;
    const __half2* xr = reinterpret_cast<const __half2*>(&Xh[c][0]);
#pragma unroll 4
    for (int p4 = 0; p4 < 16; p4++) {
      float2 x01 = __half22float2(xr[p4 * 2]);
      float2 x23 = __half22float2(xr[p4 * 2 + 1]);
      float xa[4] = {x01.x, x01.y, x23.x, x23.y};
#pragma unroll
      for (int e = 0; e < 4; e++) {
        const float4* wr = reinterpret_cast<const float4*>(&Wl[p4 * 4 + e][0]);
        float4 w0 = wr[0], w1 = wr[1];
        acc[0] += xa[e] * w0.x; acc[1] += xa[e] * w0.y;
        acc[2] += xa[e] * w0.z; acc[3] += xa[e] * w0.w;
        acc[4] += xa[e] * w1.x; acc[5] += xa[e] * w1.y;
        acc[6] += xa[e] * w1.z; acc[7] += xa[e] * w1.w;
      }
    }
    float* yp = Y + (size_t)b * NH * C;
#pragma unroll
    for (int h = 0; h < 8; h++) atomicAdd(&yp[h * C + c], acc[h]);
  }
}

// ---------------- kernel 4: o_pre = Wv·Y/nW + bv ; final = Wo·o_pre + bo ----------------
__global__ __launch_bounds__(384) void k_head(const float* __restrict__ Y,
                                              const float* __restrict__ Wv,
                                              const float* __restrict__ bv,
                                              const float* __restrict__ Wo,
                                              const float* __restrict__ bo,
                                              float* __restrict__ Fin) {
  int b = blockIdx.x;
  int o = threadIdx.x;                 // 384 threads
  __shared__ float op[C];
  int h = o / HD;
  const float* y = Y + (size_t)(b * NH + h) * C;
  const float* w = Wv + (size_t)o * C;
  float s = 0.f;
  for (int c = 0; c < C; c++) s += w[c] * y[c];
  op[o] = s * (1.0f / 1024.0f) + bv[o];
  __syncthreads();
  const float* w2 = Wo + (size_t)o * C;
  float s2 = bo[o];
  for (int c = 0; c < C; c++) s2 += w2[c] * op[c];
  Fin[b * C + o] = s2;
}

// ---------------- kernel 5: broadcast (B,C) -> (B,C,H,W) ----------------
__global__ __launch_bounds__(256) void k_bcast(const float* __restrict__ Fin,
                                               float* __restrict__ Out) {
  int bc = blockIdx.x;
  float v = Fin[bc];
  float4 v4 = make_float4(v, v, v, v);
  float4* op = reinterpret_cast<float4*>(Out + (size_t)bc * HW);
  for (int it = threadIdx.x; it < HW / 4; it += 256) op[it] = v4;
}

}  // namespace

extern "C" void kernel_launch(void* const* d_in, const int* in_sizes, int n_in,
                              void* d_out, int out_size, void* d_ws, size_t ws_size,
                              hipStream_t stream) {
  const float* Xf = (const float*)d_in[0];
  const float* Xs = (const float*)d_in[1];
  const float* Wq = (const float*)d_in[2];
  const float* bq = (const float*)d_in[3];
  const float* Wk = (const float*)d_in[4];
  // d_in[5] = bk : softmax-invariant, unused
  const float* Wv = (const float*)d_in[6];
  const float* bv = (const float*)d_in[7];
  const float* Wo = (const float*)d_in[8];
  const float* bo = (const float*)d_in[9];
  float* Out = (float*)d_out;

  char* ws = (char*)d_ws;
  float* Qg = (float*)(ws);                        // 6 KB
  float* Qk = (float*)(ws + 8192);                 // 48 KB  [b][c][h]
  float* Y  = (float*)(ws + 8192 + 65536);         // 48 KB  [b][h][c]
  float* Fin = (float*)(ws + 8192 + 131072);       // 6 KB

  k_mean<<<B * C, 256, 0, stream>>>(Xf, Qg);
  k_proj<<<1, 256, 0, stream>>>(Qg, Wq, bq, Wk, Qk, Y);
  k_attn<<<B * 1024, 256, 0, stream>>>(Xs, Qk, Y);
  k_head<<<B, 384, 0, stream>>>(Y, Wv, bv, Wo, bo, Fin);
  k_bcast<<<B * C, 256, 0, stream>>>(Fin, Out);
}